// Round 2
// baseline (261.668 us; speedup 1.0000x reference)
//
#include <hip/hip_runtime.h>

#define K_TAPS   61
#define R_OUT    7
#define BLOCK    256
#define TILE_OUT (BLOCK * R_OUT)           // 1792 outputs per block
#define TILE_IN  (TILE_OUT + K_TAPS - 1)   // 1852 inputs per block (divisible by 4)

__global__ __launch_bounds__(BLOCK)
void SpikeToCalcium_conv1d_kernel(const float* __restrict__ u,
                                  const float* __restrict__ kern,
                                  float* __restrict__ out,
                                  int L, int M, long long total_in)
{
    __shared__ float sx[TILE_IN];
    __shared__ float sk[K_TAPS];

    const int t          = threadIdx.x;
    const int row        = blockIdx.y;
    const int tile_start = blockIdx.x * TILE_OUT;

    // Stage reversed taps: sk[k] = kern[K-1-k] so out[n] = sum_k sx[n+k]*sk[k]
    if (t < K_TAPS) sk[t] = kern[K_TAPS - 1 - t];

    // Stage input tile, vectorized float4 (aligned: L%4==0 and TILE_OUT%4==0).
    // Over-read into the next row is harmless (feeds only masked outputs);
    // only guard against running past the end of the whole buffer.
    const long long gbase = (long long)row * L + tile_start;
    for (int v = t; v < TILE_IN / 4; v += BLOCK) {
        const long long g = gbase + 4LL * v;
        float4 val;
        if (g + 3 < total_in) {
            val = *reinterpret_cast<const float4*>(u + g);
        } else {
            val.x = (g + 0 < total_in) ? u[g + 0] : 0.0f;
            val.y = (g + 1 < total_in) ? u[g + 1] : 0.0f;
            val.z = (g + 2 < total_in) ? u[g + 2] : 0.0f;
            val.w = (g + 3 < total_in) ? u[g + 3] : 0.0f;
        }
        *reinterpret_cast<float4*>(sx + 4 * v) = val;
    }
    __syncthreads();

    // Each thread computes R_OUT=7 consecutive outputs via a sliding register
    // window. LDS lane stride = 7 floats (coprime with 32 banks -> 2-way, free).
    // Full k-unroll makes the window shifts pure register renaming (no movs).
    const int off = t * R_OUT;

    float acc[R_OUT];
    float w[R_OUT];
#pragma unroll
    for (int r = 0; r < R_OUT; ++r) acc[r] = 0.0f;
#pragma unroll
    for (int r = 0; r < R_OUT; ++r) w[r] = sx[off + r];

#pragma unroll
    for (int k = 0; k < K_TAPS; ++k) {
        const float kv = sk[k];
#pragma unroll
        for (int r = 0; r < R_OUT; ++r) acc[r] = fmaf(w[r], kv, acc[r]);
        if (k < K_TAPS - 1) {
#pragma unroll
            for (int r = 0; r < R_OUT - 1; ++r) w[r] = w[r + 1];
            w[R_OUT - 1] = sx[off + k + R_OUT];  // ds_read base + imm offset
        }
    }

    // Store 7 consecutive outputs (masked at the row tail).
    const long long orow = (long long)row * M;
    const int nbase = tile_start + off;
#pragma unroll
    for (int r = 0; r < R_OUT; ++r) {
        const int n = nbase + r;
        if (n < M) out[orow + n] = acc[r];
    }
}

extern "C" void kernel_launch(void* const* d_in, const int* in_sizes, int n_in,
                              void* d_out, int out_size, void* d_ws, size_t ws_size,
                              hipStream_t stream) {
    const float* u    = (const float*)d_in[0];
    const float* kern = (const float*)d_in[1];
    float*       out  = (float*)d_out;

    const long long total_in = (long long)in_sizes[0];
    // total_in = R*L, out_size = R*(L-K+1)  =>  R = (total_in - out_size)/(K-1)
    const int ROWS = (int)((total_in - (long long)out_size) / (K_TAPS - 1)); // 1024
    const int L    = (int)(total_in / ROWS);                                 // 30000
    const int M    = L - K_TAPS + 1;                                         // 29940

    const int blocks_per_row = (M + TILE_OUT - 1) / TILE_OUT;  // 17
    dim3 grid(blocks_per_row, ROWS);
    SpikeToCalcium_conv1d_kernel<<<grid, BLOCK, 0, stream>>>(
        u, kern, out, L, M, total_in);
}